// Round 1
// baseline (526.757 us; speedup 1.0000x reference)
//
#include <hip/hip_runtime.h>
#include <hip/hip_bf16.h>
#include <math.h>

// ---------------- helpers ----------------

__device__ __forceinline__ float wave_max64(float v) {
#pragma unroll
  for (int o = 32; o > 0; o >>= 1) v = fmaxf(v, __shfl_xor(v, o));
  return v;
}
__device__ __forceinline__ float wave_sum64(float v) {
#pragma unroll
  for (int o = 32; o > 0; o >>= 1) v += __shfl_xor(v, o);
  return v;
}
__device__ __forceinline__ float leaky02(float v) { return v > 0.0f ? v : 0.2f * v; }

// ---------------- CSR build ----------------

__global__ void hist_kernel(const int* __restrict__ ei, int* __restrict__ counts, int E) {
  int e = blockIdx.x * blockDim.x + threadIdx.x;
  if (e < E) atomicAdd(&counts[ei[E + e]], 1);
}

// single-block scan over N counts -> exclusive prefix (row_start) + cursor copy
__global__ void scan_kernel(const int* __restrict__ counts, int* __restrict__ row_start,
                            int* __restrict__ cursor, int N) {
  __shared__ int lds[1024];
  __shared__ int s_carry;
  if (threadIdx.x == 0) s_carry = 0;
  __syncthreads();
  for (int base = 0; base < N; base += 1024) {
    int i = base + (int)threadIdx.x;
    int v = (i < N) ? counts[i] : 0;
    lds[threadIdx.x] = v;
    __syncthreads();
#pragma unroll
    for (int off = 1; off < 1024; off <<= 1) {
      int t = ((int)threadIdx.x >= off) ? lds[threadIdx.x - off] : 0;
      __syncthreads();
      lds[threadIdx.x] += t;
      __syncthreads();
    }
    int incl = lds[threadIdx.x];
    int carry = s_carry;
    __syncthreads();
    if (i < N) {
      int excl = carry + incl - v;
      row_start[i] = excl;
      cursor[i] = excl;
    }
    if (threadIdx.x == 1023) s_carry = carry + lds[1023];
    __syncthreads();
  }
  if (threadIdx.x == 0) row_start[N] = s_carry;
}

__global__ void scatter_kernel(const int* __restrict__ ei, int* __restrict__ cursor,
                               int* __restrict__ esrc, int E) {
  int e = blockIdx.x * blockDim.x + threadIdx.x;
  if (e < E) {
    int dst = ei[E + e];
    int pos = atomicAdd(&cursor[dst], 1);
    esrc[pos] = ei[e];
  }
}

// ---------------- GEMM 1: H1 = X @ W1, plus per-node logit dots ----------------
// block = 256 (4 waves), 4 rows per wave => 16 rows/block. W (128x128) in LDS.

__global__ __launch_bounds__(256) void gemm1_kernel(
    const float* __restrict__ X, const float* __restrict__ W,
    const float* __restrict__ a_src, const float* __restrict__ a_dst,
    float* __restrict__ H, float* __restrict__ asrc, float* __restrict__ adst, int N) {
  __shared__ float Ws[128 * 128];
  {
    const float4* Wv = (const float4*)W;
    float4* Wsv = (float4*)Ws;
    for (int i = threadIdx.x; i < 128 * 128 / 4; i += 256) Wsv[i] = Wv[i];
  }
  __syncthreads();
  int wid = threadIdx.x >> 6, lane = threadIdx.x & 63;
  int row0 = (blockIdx.x * 4 + wid) * 4;
  if (row0 >= N) return;

  float2 acc[4];
  float2 xv[4];
#pragma unroll
  for (int r = 0; r < 4; ++r) {
    acc[r].x = 0.f; acc[r].y = 0.f;
    int row = row0 + r;
    if (row < N) xv[r] = ((const float2*)(X + (size_t)row * 128))[lane];
    else { xv[r].x = 0.f; xv[r].y = 0.f; }
  }
#pragma unroll 8
  for (int k = 0; k < 128; k += 2) {
    int sl = k >> 1;
    float2 w0 = *(const float2*)&Ws[k * 128 + 2 * lane];
    float2 w1 = *(const float2*)&Ws[(k + 1) * 128 + 2 * lane];
#pragma unroll
    for (int r = 0; r < 4; ++r) {
      float x0 = __shfl(xv[r].x, sl);
      float x1 = __shfl(xv[r].y, sl);
      acc[r].x = fmaf(x1, w1.x, fmaf(x0, w0.x, acc[r].x));
      acc[r].y = fmaf(x1, w1.y, fmaf(x0, w0.y, acc[r].y));
    }
  }
  float2 av = ((const float2*)a_src)[lane];
  float2 dv = ((const float2*)a_dst)[lane];
#pragma unroll
  for (int r = 0; r < 4; ++r) {
    int row = row0 + r;
    if (row >= N) break;
    ((float2*)(H + (size_t)row * 128))[lane] = acc[r];
    float ps = acc[r].x * av.x + acc[r].y * av.y;
    float pd = acc[r].x * dv.x + acc[r].y * dv.y;
#pragma unroll
    for (int o = 32; o > 0; o >>= 1) {
      ps += __shfl_xor(ps, o);
      pd += __shfl_xor(pd, o);
    }
    if (lane == 0) { asrc[row] = ps; adst[row] = pd; }
  }
}

// ---------------- GEMM 2: H2 = h @ [W_mu | W_ls], plus 4 logit dot vectors ----------------

__global__ __launch_bounds__(256) void gemm2_kernel(
    const float* __restrict__ X,
    const float* __restrict__ W_mu, const float* __restrict__ W_ls,
    const float* __restrict__ a_src_mu, const float* __restrict__ a_dst_mu,
    const float* __restrict__ a_src_ls, const float* __restrict__ a_dst_ls,
    float* __restrict__ H,
    float* __restrict__ asmu, float* __restrict__ admu,
    float* __restrict__ asls, float* __restrict__ adls, int N) {
  __shared__ float Ws[128 * 128];
  {
    for (int i = threadIdx.x; i < 128 * 64 / 4; i += 256) {
      int idx = i * 4;
      int k = idx >> 6;
      int c = idx & 63;
      float4 vmu = ((const float4*)W_mu)[i];
      float4 vls = ((const float4*)W_ls)[i];
      *(float4*)&Ws[k * 128 + c] = vmu;
      *(float4*)&Ws[k * 128 + 64 + c] = vls;
    }
  }
  __syncthreads();
  int wid = threadIdx.x >> 6, lane = threadIdx.x & 63;
  int row0 = (blockIdx.x * 4 + wid) * 4;
  if (row0 >= N) return;

  float2 acc[4];
  float2 xv[4];
#pragma unroll
  for (int r = 0; r < 4; ++r) {
    acc[r].x = 0.f; acc[r].y = 0.f;
    int row = row0 + r;
    if (row < N) xv[r] = ((const float2*)(X + (size_t)row * 128))[lane];
    else { xv[r].x = 0.f; xv[r].y = 0.f; }
  }
#pragma unroll 8
  for (int k = 0; k < 128; k += 2) {
    int sl = k >> 1;
    float2 w0 = *(const float2*)&Ws[k * 128 + 2 * lane];
    float2 w1 = *(const float2*)&Ws[(k + 1) * 128 + 2 * lane];
#pragma unroll
    for (int r = 0; r < 4; ++r) {
      float x0 = __shfl(xv[r].x, sl);
      float x1 = __shfl(xv[r].y, sl);
      acc[r].x = fmaf(x1, w1.x, fmaf(x0, w0.x, acc[r].x));
      acc[r].y = fmaf(x1, w1.y, fmaf(x0, w0.y, acc[r].y));
    }
  }
  bool isMu = lane < 32;
  float2 av, dv;
  if (isMu) {
    av = ((const float2*)a_src_mu)[lane];
    dv = ((const float2*)a_dst_mu)[lane];
  } else {
    av = ((const float2*)a_src_ls)[lane - 32];
    dv = ((const float2*)a_dst_ls)[lane - 32];
  }
#pragma unroll
  for (int r = 0; r < 4; ++r) {
    int row = row0 + r;
    if (row >= N) break;
    ((float2*)(H + (size_t)row * 128))[lane] = acc[r];
    float ps = acc[r].x * av.x + acc[r].y * av.y;
    float pd = acc[r].x * dv.x + acc[r].y * dv.y;
#pragma unroll
    for (int o = 16; o > 0; o >>= 1) {  // reduce within each 32-lane half
      ps += __shfl_xor(ps, o);
      pd += __shfl_xor(pd, o);
    }
    if (lane == 0) { asmu[row] = ps; admu[row] = pd; }
    if (lane == 32) { asls[row] = ps; adls[row] = pd; }
  }
}

// ---------------- Aggregation layer 1 (C=128, + bias + ReLU) ----------------
// one wave per destination node; online softmax incl. implicit self-loop

__global__ __launch_bounds__(256) void agg1_kernel(
    const float* __restrict__ H, const float* __restrict__ asrc, const float* __restrict__ adst,
    const int* __restrict__ row_start, const int* __restrict__ esrc,
    const float* __restrict__ b, float* __restrict__ hout, int N) {
  int lane = threadIdx.x & 63;
  int d = (int)((blockIdx.x * blockDim.x + threadIdx.x) >> 6);
  if (d >= N) return;
  float ad = adst[d];
  float m = leaky02(asrc[d] + ad);  // self-loop logit
  float denom = 1.0f;
  float2 acc = ((const float2*)(H + (size_t)d * 128))[lane];  // weight 1 (= exp(e_self - m))
  int beg = row_start[d], end = row_start[d + 1];
  for (int base = beg; base < end; base += 64) {
    int nv = end - base;
    if (nv > 64) nv = 64;
    float e = -INFINITY;
    int s = 0;
    if (lane < nv) {
      s = esrc[base + lane];
      e = leaky02(asrc[s] + ad);
    }
    float cm = wave_max64(e);
    if (cm > m) {
      float sc = __expf(m - cm);
      denom *= sc; acc.x *= sc; acc.y *= sc;
      m = cm;
    }
    float w = __expf(e - m);  // 0 for invalid lanes
    denom += wave_sum64(w);
    for (int j = 0; j < nv; ++j) {
      float wj = __shfl(w, j);
      int sj = __shfl(s, j);
      float2 hv = ((const float2*)(H + (size_t)sj * 128))[lane];
      acc.x = fmaf(wj, hv.x, acc.x);
      acc.y = fmaf(wj, hv.y, acc.y);
    }
  }
  float inv = 1.0f / denom;
  float2 bv = ((const float2*)b)[lane];
  float2 o;
  o.x = fmaxf(fmaf(acc.x, inv, bv.x), 0.0f);
  o.y = fmaxf(fmaf(acc.y, inv, bv.y), 0.0f);
  ((float2*)(hout + (size_t)d * 128))[lane] = o;
}

// ---------------- Aggregation layers 2+3 fused (mu lanes 0-31, ls lanes 32-63) ----------------

__global__ __launch_bounds__(256) void agg2_kernel(
    const float* __restrict__ H2,
    const float* __restrict__ asmu, const float* __restrict__ admu,
    const float* __restrict__ asls, const float* __restrict__ adls,
    const int* __restrict__ row_start, const int* __restrict__ esrc,
    const float* __restrict__ b_mu, const float* __restrict__ b_ls,
    float* __restrict__ out_mu, float* __restrict__ out_ls, int N) {
  int lane = threadIdx.x & 63;
  int d = (int)((blockIdx.x * blockDim.x + threadIdx.x) >> 6);
  if (d >= N) return;
  bool isMu = lane < 32;
  float admu_d = admu[d], adls_d = adls[d];
  float m_mu = leaky02(asmu[d] + admu_d);
  float m_ls = leaky02(asls[d] + adls_d);
  float den_mu = 1.0f, den_ls = 1.0f;
  float2 acc = ((const float2*)(H2 + (size_t)d * 128))[lane];
  int beg = row_start[d], end = row_start[d + 1];
  for (int base = beg; base < end; base += 64) {
    int nv = end - base;
    if (nv > 64) nv = 64;
    float e_mu = -INFINITY, e_ls = -INFINITY;
    int s = 0;
    if (lane < nv) {
      s = esrc[base + lane];
      e_mu = leaky02(asmu[s] + admu_d);
      e_ls = leaky02(asls[s] + adls_d);
    }
    float cm_mu = wave_max64(e_mu);
    float cm_ls = wave_max64(e_ls);
    float sc_mu = 1.0f, sc_ls = 1.0f;
    if (cm_mu > m_mu) { sc_mu = __expf(m_mu - cm_mu); den_mu *= sc_mu; m_mu = cm_mu; }
    if (cm_ls > m_ls) { sc_ls = __expf(m_ls - cm_ls); den_ls *= sc_ls; m_ls = cm_ls; }
    float sc = isMu ? sc_mu : sc_ls;
    acc.x *= sc; acc.y *= sc;
    float w_mu = __expf(e_mu - m_mu);
    float w_ls = __expf(e_ls - m_ls);
    den_mu += wave_sum64(w_mu);
    den_ls += wave_sum64(w_ls);
    for (int j = 0; j < nv; ++j) {
      float wj_mu = __shfl(w_mu, j);
      float wj_ls = __shfl(w_ls, j);
      float wj = isMu ? wj_mu : wj_ls;
      int sj = __shfl(s, j);
      float2 hv = ((const float2*)(H2 + (size_t)sj * 128))[lane];
      acc.x = fmaf(wj, hv.x, acc.x);
      acc.y = fmaf(wj, hv.y, acc.y);
    }
  }
  float inv = isMu ? (1.0f / den_mu) : (1.0f / den_ls);
  float2 bv = isMu ? ((const float2*)b_mu)[lane] : ((const float2*)b_ls)[lane - 32];
  float2 o;
  o.x = fmaf(acc.x, inv, bv.x);
  o.y = fmaf(acc.y, inv, bv.y);
  if (isMu) ((float2*)(out_mu + (size_t)d * 64))[lane] = o;
  else      ((float2*)(out_ls + (size_t)d * 64))[lane - 32] = o;
}

// ---------------- launch ----------------

extern "C" void kernel_launch(void* const* d_in, const int* in_sizes, int n_in,
                              void* d_out, int out_size, void* d_ws, size_t ws_size,
                              hipStream_t stream) {
  const float* x = (const float*)d_in[0];
  const int* ei = (const int*)d_in[1];
  const float* W1 = (const float*)d_in[2];
  const float* a_src1 = (const float*)d_in[3];
  const float* a_dst1 = (const float*)d_in[4];
  const float* b1 = (const float*)d_in[5];
  const float* W_mu = (const float*)d_in[6];
  const float* a_src_mu = (const float*)d_in[7];
  const float* a_dst_mu = (const float*)d_in[8];
  const float* b_mu = (const float*)d_in[9];
  const float* W_ls = (const float*)d_in[10];
  const float* a_src_ls = (const float*)d_in[11];
  const float* a_dst_ls = (const float*)d_in[12];
  const float* b_ls = (const float*)d_in[13];

  const int N = in_sizes[0] / 128;  // 50000
  const int E = in_sizes[1] / 2;    // 800000

  uint8_t* p = (uint8_t*)d_ws;
  auto carve = [&](size_t bytes) -> void* {
    void* q = (void*)p;
    p += (bytes + 255) & ~(size_t)255;
    return q;
  };
  int* counts = (int*)carve((size_t)N * 4);
  int* row_start = (int*)carve((size_t)(N + 1) * 4);
  int* cursor = (int*)carve((size_t)N * 4);
  int* esrc = (int*)carve((size_t)E * 4);
  float* H1 = (float*)carve((size_t)N * 128 * 4);  // also reused as H2
  float* h1 = (float*)carve((size_t)N * 128 * 4);
  float* as1 = (float*)carve((size_t)N * 4);
  float* ad1 = (float*)carve((size_t)N * 4);
  float* asmu = (float*)carve((size_t)N * 4);
  float* admu = (float*)carve((size_t)N * 4);
  float* asls = (float*)carve((size_t)N * 4);
  float* adls = (float*)carve((size_t)N * 4);

  float* H2 = H1;  // H1 dead after agg1; reuse for the fused mu|ls features

  hipMemsetAsync(counts, 0, (size_t)N * 4, stream);
  hist_kernel<<<(E + 255) / 256, 256, 0, stream>>>(ei, counts, E);
  scan_kernel<<<1, 1024, 0, stream>>>(counts, row_start, cursor, N);
  scatter_kernel<<<(E + 255) / 256, 256, 0, stream>>>(ei, cursor, esrc, E);

  gemm1_kernel<<<(N + 15) / 16, 256, 0, stream>>>(x, W1, a_src1, a_dst1, H1, as1, ad1, N);
  agg1_kernel<<<(N + 3) / 4, 256, 0, stream>>>(H1, as1, ad1, row_start, esrc, b1, h1, N);
  gemm2_kernel<<<(N + 15) / 16, 256, 0, stream>>>(h1, W_mu, W_ls, a_src_mu, a_dst_mu,
                                                  a_src_ls, a_dst_ls, H2, asmu, admu, asls, adls, N);
  float* out_mu = (float*)d_out;
  float* out_ls = out_mu + (size_t)N * 64;
  agg2_kernel<<<(N + 3) / 4, 256, 0, stream>>>(H2, asmu, admu, asls, adls, row_start, esrc,
                                               b_mu, b_ls, out_mu, out_ls, N);
}

// Round 2
// 314.133 us; speedup vs baseline: 1.6769x; 1.6769x over previous
//
#include <hip/hip_runtime.h>
#include <hip/hip_bf16.h>
#include <math.h>

// ---------------- helpers ----------------

__device__ __forceinline__ float wave_max64(float v) {
#pragma unroll
  for (int o = 32; o > 0; o >>= 1) v = fmaxf(v, __shfl_xor(v, o));
  return v;
}
__device__ __forceinline__ float wave_sum64(float v) {
#pragma unroll
  for (int o = 32; o > 0; o >>= 1) v += __shfl_xor(v, o);
  return v;
}
__device__ __forceinline__ float leaky02(float v) { return v > 0.0f ? v : 0.2f * v; }

// ---------------- CSR build ----------------

__global__ void hist_kernel(const int* __restrict__ ei, int* __restrict__ counts, int E) {
  int e = blockIdx.x * blockDim.x + threadIdx.x;
  if (e < E) atomicAdd(&counts[ei[E + e]], 1);
}

// per-block exclusive scan piece: writes excl[i] (within-block) + blockSums[b]
__global__ __launch_bounds__(256) void scan_block_kernel(
    const int* __restrict__ counts, int* __restrict__ excl, int* __restrict__ blockSums, int N) {
  __shared__ int lds[256];
  int i = blockIdx.x * 256 + threadIdx.x;
  int v = (i < N) ? counts[i] : 0;
  lds[threadIdx.x] = v;
  __syncthreads();
#pragma unroll
  for (int off = 1; off < 256; off <<= 1) {
    int t = ((int)threadIdx.x >= off) ? lds[threadIdx.x - off] : 0;
    __syncthreads();
    lds[threadIdx.x] += t;
    __syncthreads();
  }
  if (i < N) excl[i] = lds[threadIdx.x] - v;
  if (threadIdx.x == 255) blockSums[blockIdx.x] = lds[255];
}

// single small block: exclusive-scan blockSums (NB<=256) in place; writes total to row_start[N]
__global__ __launch_bounds__(256) void scan_sums_kernel(
    int* __restrict__ blockSums, int* __restrict__ row_start, int NB, int N) {
  __shared__ int lds[256];
  int b = threadIdx.x;
  int v = (b < NB) ? blockSums[b] : 0;
  lds[b] = v;
  __syncthreads();
#pragma unroll
  for (int off = 1; off < 256; off <<= 1) {
    int t = ((int)threadIdx.x >= off) ? lds[threadIdx.x - off] : 0;
    __syncthreads();
    lds[threadIdx.x] += t;
    __syncthreads();
  }
  if (b < NB) blockSums[b] = lds[b] - v;  // exclusive offset
  if (b == NB - 1) row_start[N] = lds[b];
}

__global__ __launch_bounds__(256) void scan_final_kernel(
    const int* __restrict__ excl, const int* __restrict__ blockSums,
    int* __restrict__ row_start, int* __restrict__ cursor, int N) {
  int i = blockIdx.x * 256 + threadIdx.x;
  if (i < N) {
    int rs = excl[i] + blockSums[blockIdx.x];
    row_start[i] = rs;
    cursor[i] = rs;
  }
}

__global__ void scatter_kernel(const int* __restrict__ ei, int* __restrict__ cursor,
                               int* __restrict__ esrc, int E) {
  int e = blockIdx.x * blockDim.x + threadIdx.x;
  if (e < E) {
    int dst = ei[E + e];
    int pos = atomicAdd(&cursor[dst], 1);
    esrc[pos] = ei[e];
  }
}

// ---------------- GEMM: register-blocked, LDS tiled ----------------
// 256 threads; M_TILE=64 rows, N=128 cols, K=128 in chunks of 32.
// tx = tid&15 owns cols tx*8..+7; ty = tid>>4 owns rows ty*4..+3. acc[4][8].
// Xs stored K-major with XOR swizzle; Ws row-major [k][128].

#define XIDX(k, m) ((k) * 64 + ((m) ^ ((((k) >> 2) & 7) << 3)))

__global__ __launch_bounds__(256) void gemm1_kernel(
    const float* __restrict__ X, const float* __restrict__ W,
    const float* __restrict__ a_src, const float* __restrict__ a_dst,
    float* __restrict__ H, float* __restrict__ asrc, float* __restrict__ adst, int N) {
  __shared__ float Xs[32 * 64];
  __shared__ float Ws[32 * 128];
  const int tid = threadIdx.x;
  const int tx = tid & 15, ty = tid >> 4;
  const int rowBase = blockIdx.x * 64;
  const int c0 = tx * 8;

  float acc[4][8];
#pragma unroll
  for (int r = 0; r < 4; ++r)
#pragma unroll
    for (int c = 0; c < 8; ++c) acc[r][c] = 0.f;

  for (int kc = 0; kc < 4; ++kc) {
    const int k0 = kc * 32;
    // stage X chunk transposed+swizzled: 512 float4, 2 per thread
#pragma unroll
    for (int j = 0; j < 2; ++j) {
      int i = tid + j * 256;
      int m = i >> 3, kq = i & 7;
      int row = rowBase + m;
      float4 v = make_float4(0.f, 0.f, 0.f, 0.f);
      if (row < N) v = *(const float4*)(X + (size_t)row * 128 + k0 + kq * 4);
      Xs[XIDX(kq * 4 + 0, m)] = v.x;
      Xs[XIDX(kq * 4 + 1, m)] = v.y;
      Xs[XIDX(kq * 4 + 2, m)] = v.z;
      Xs[XIDX(kq * 4 + 3, m)] = v.w;
    }
    // stage W chunk: 32x128 floats = 1024 float4, 4 per thread
#pragma unroll
    for (int j = 0; j < 4; ++j) {
      int i = tid + j * 256;
      int k = i >> 5, c = (i & 31) * 4;
      *(float4*)&Ws[k * 128 + c] = *(const float4*)(W + (size_t)(k0 + k) * 128 + c);
    }
    __syncthreads();
#pragma unroll
    for (int k = 0; k < 32; ++k) {
      float4 a = *(const float4*)&Xs[k * 64 + ((ty * 4) ^ (((k >> 2) & 7) << 3))];
      float4 b0 = *(const float4*)&Ws[k * 128 + c0];
      float4 b1 = *(const float4*)&Ws[k * 128 + c0 + 4];
      float av[4] = {a.x, a.y, a.z, a.w};
      float bv[8] = {b0.x, b0.y, b0.z, b0.w, b1.x, b1.y, b1.z, b1.w};
#pragma unroll
      for (int r = 0; r < 4; ++r)
#pragma unroll
        for (int c = 0; c < 8; ++c) acc[r][c] = fmaf(av[r], bv[c], acc[r][c]);
    }
    __syncthreads();
  }

  // epilogue: store H rows + per-row logit dots (reduce over tx: lane bits 0..3)
  float as[8], ds[8];
#pragma unroll
  for (int c = 0; c < 8; ++c) { as[c] = a_src[c0 + c]; ds[c] = a_dst[c0 + c]; }
#pragma unroll
  for (int r = 0; r < 4; ++r) {
    int row = rowBase + ty * 4 + r;
    if (row >= N) break;
    *(float4*)(H + (size_t)row * 128 + c0) = make_float4(acc[r][0], acc[r][1], acc[r][2], acc[r][3]);
    *(float4*)(H + (size_t)row * 128 + c0 + 4) = make_float4(acc[r][4], acc[r][5], acc[r][6], acc[r][7]);
    float ps = 0.f, pd = 0.f;
#pragma unroll
    for (int c = 0; c < 8; ++c) { ps = fmaf(acc[r][c], as[c], ps); pd = fmaf(acc[r][c], ds[c], pd); }
#pragma unroll
    for (int o = 8; o > 0; o >>= 1) { ps += __shfl_xor(ps, o); pd += __shfl_xor(pd, o); }
    if (tx == 0) { asrc[row] = ps; adst[row] = pd; }
  }
}

__global__ __launch_bounds__(256) void gemm2_kernel(
    const float* __restrict__ X,
    const float* __restrict__ W_mu, const float* __restrict__ W_ls,
    const float* __restrict__ a_src_mu, const float* __restrict__ a_dst_mu,
    const float* __restrict__ a_src_ls, const float* __restrict__ a_dst_ls,
    float* __restrict__ H,
    float* __restrict__ asmu, float* __restrict__ admu,
    float* __restrict__ asls, float* __restrict__ adls, int N) {
  __shared__ float Xs[32 * 64];
  __shared__ float Ws[32 * 128];
  const int tid = threadIdx.x;
  const int tx = tid & 15, ty = tid >> 4;
  const int rowBase = blockIdx.x * 64;
  const int c0 = tx * 8;
  const bool isMu = tx < 8;

  float acc[4][8];
#pragma unroll
  for (int r = 0; r < 4; ++r)
#pragma unroll
    for (int c = 0; c < 8; ++c) acc[r][c] = 0.f;

  for (int kc = 0; kc < 4; ++kc) {
    const int k0 = kc * 32;
#pragma unroll
    for (int j = 0; j < 2; ++j) {
      int i = tid + j * 256;
      int m = i >> 3, kq = i & 7;
      int row = rowBase + m;
      float4 v = make_float4(0.f, 0.f, 0.f, 0.f);
      if (row < N) v = *(const float4*)(X + (size_t)row * 128 + k0 + kq * 4);
      Xs[XIDX(kq * 4 + 0, m)] = v.x;
      Xs[XIDX(kq * 4 + 1, m)] = v.y;
      Xs[XIDX(kq * 4 + 2, m)] = v.z;
      Xs[XIDX(kq * 4 + 3, m)] = v.w;
    }
    // stage [W_mu | W_ls] chunk: each matrix 32x64 = 512 float4, 2 per thread each
#pragma unroll
    for (int j = 0; j < 2; ++j) {
      int i = tid + j * 256;
      int k = i >> 4, c = (i & 15) * 4;
      *(float4*)&Ws[k * 128 + c] = *(const float4*)(W_mu + (size_t)(k0 + k) * 64 + c);
      *(float4*)&Ws[k * 128 + 64 + c] = *(const float4*)(W_ls + (size_t)(k0 + k) * 64 + c);
    }
    __syncthreads();
#pragma unroll
    for (int k = 0; k < 32; ++k) {
      float4 a = *(const float4*)&Xs[k * 64 + ((ty * 4) ^ (((k >> 2) & 7) << 3))];
      float4 b0 = *(const float4*)&Ws[k * 128 + c0];
      float4 b1 = *(const float4*)&Ws[k * 128 + c0 + 4];
      float av[4] = {a.x, a.y, a.z, a.w};
      float bv[8] = {b0.x, b0.y, b0.z, b0.w, b1.x, b1.y, b1.z, b1.w};
#pragma unroll
      for (int r = 0; r < 4; ++r)
#pragma unroll
        for (int c = 0; c < 8; ++c) acc[r][c] = fmaf(av[r], bv[c], acc[r][c]);
    }
    __syncthreads();
  }

  float as[8], ds[8];
#pragma unroll
  for (int c = 0; c < 8; ++c) {
    int cc = isMu ? (c0 + c) : (c0 - 64 + c);
    as[c] = isMu ? a_src_mu[cc] : a_src_ls[cc];
    ds[c] = isMu ? a_dst_mu[cc] : a_dst_ls[cc];
  }
#pragma unroll
  for (int r = 0; r < 4; ++r) {
    int row = rowBase + ty * 4 + r;
    if (row >= N) break;
    *(float4*)(H + (size_t)row * 128 + c0) = make_float4(acc[r][0], acc[r][1], acc[r][2], acc[r][3]);
    *(float4*)(H + (size_t)row * 128 + c0 + 4) = make_float4(acc[r][4], acc[r][5], acc[r][6], acc[r][7]);
    float ps = 0.f, pd = 0.f;
#pragma unroll
    for (int c = 0; c < 8; ++c) { ps = fmaf(acc[r][c], as[c], ps); pd = fmaf(acc[r][c], ds[c], pd); }
#pragma unroll
    for (int o = 4; o > 0; o >>= 1) { ps += __shfl_xor(ps, o); pd += __shfl_xor(pd, o); }
    if (tx == 0) { asmu[row] = ps; admu[row] = pd; }
    if (tx == 8) { asls[row] = ps; adls[row] = pd; }
  }
}

// ---------------- Aggregation layer 1 (C=128, + bias + ReLU) ----------------

__global__ __launch_bounds__(256) void agg1_kernel(
    const float* __restrict__ H, const float* __restrict__ asrc, const float* __restrict__ adst,
    const int* __restrict__ row_start, const int* __restrict__ esrc,
    const float* __restrict__ b, float* __restrict__ hout, int N) {
  int lane = threadIdx.x & 63;
  int d = (int)((blockIdx.x * blockDim.x + threadIdx.x) >> 6);
  if (d >= N) return;
  float ad = adst[d];
  float m = leaky02(asrc[d] + ad);  // self-loop logit
  float denom = 1.0f;
  float2 acc = ((const float2*)(H + (size_t)d * 128))[lane];
  int beg = row_start[d], end = row_start[d + 1];
  for (int base = beg; base < end; base += 64) {
    int nv = end - base;
    if (nv > 64) nv = 64;
    float e = -INFINITY;
    int s = 0;
    if (lane < nv) {
      s = esrc[base + lane];
      e = leaky02(asrc[s] + ad);
    }
    float cm = wave_max64(e);
    if (cm > m) {
      float sc = __expf(m - cm);
      denom *= sc; acc.x *= sc; acc.y *= sc;
      m = cm;
    }
    float w = __expf(e - m);
    denom += wave_sum64(w);
    for (int j = 0; j < nv; ++j) {
      float wj = __shfl(w, j);
      int sj = __shfl(s, j);
      float2 hv = ((const float2*)(H + (size_t)sj * 128))[lane];
      acc.x = fmaf(wj, hv.x, acc.x);
      acc.y = fmaf(wj, hv.y, acc.y);
    }
  }
  float inv = 1.0f / denom;
  float2 bv = ((const float2*)b)[lane];
  float2 o;
  o.x = fmaxf(fmaf(acc.x, inv, bv.x), 0.0f);
  o.y = fmaxf(fmaf(acc.y, inv, bv.y), 0.0f);
  ((float2*)(hout + (size_t)d * 128))[lane] = o;
}

// ---------------- Aggregation layers 2+3 fused ----------------

__global__ __launch_bounds__(256) void agg2_kernel(
    const float* __restrict__ H2,
    const float* __restrict__ asmu, const float* __restrict__ admu,
    const float* __restrict__ asls, const float* __restrict__ adls,
    const int* __restrict__ row_start, const int* __restrict__ esrc,
    const float* __restrict__ b_mu, const float* __restrict__ b_ls,
    float* __restrict__ out_mu, float* __restrict__ out_ls, int N) {
  int lane = threadIdx.x & 63;
  int d = (int)((blockIdx.x * blockDim.x + threadIdx.x) >> 6);
  if (d >= N) return;
  bool isMu = lane < 32;
  float admu_d = admu[d], adls_d = adls[d];
  float m_mu = leaky02(asmu[d] + admu_d);
  float m_ls = leaky02(asls[d] + adls_d);
  float den_mu = 1.0f, den_ls = 1.0f;
  float2 acc = ((const float2*)(H2 + (size_t)d * 128))[lane];
  int beg = row_start[d], end = row_start[d + 1];
  for (int base = beg; base < end; base += 64) {
    int nv = end - base;
    if (nv > 64) nv = 64;
    float e_mu = -INFINITY, e_ls = -INFINITY;
    int s = 0;
    if (lane < nv) {
      s = esrc[base + lane];
      e_mu = leaky02(asmu[s] + admu_d);
      e_ls = leaky02(asls[s] + adls_d);
    }
    float cm_mu = wave_max64(e_mu);
    float cm_ls = wave_max64(e_ls);
    float sc_mu = 1.0f, sc_ls = 1.0f;
    if (cm_mu > m_mu) { sc_mu = __expf(m_mu - cm_mu); den_mu *= sc_mu; m_mu = cm_mu; }
    if (cm_ls > m_ls) { sc_ls = __expf(m_ls - cm_ls); den_ls *= sc_ls; m_ls = cm_ls; }
    float sc = isMu ? sc_mu : sc_ls;
    acc.x *= sc; acc.y *= sc;
    float w_mu = __expf(e_mu - m_mu);
    float w_ls = __expf(e_ls - m_ls);
    den_mu += wave_sum64(w_mu);
    den_ls += wave_sum64(w_ls);
    for (int j = 0; j < nv; ++j) {
      float wj_mu = __shfl(w_mu, j);
      float wj_ls = __shfl(w_ls, j);
      float wj = isMu ? wj_mu : wj_ls;
      int sj = __shfl(s, j);
      float2 hv = ((const float2*)(H2 + (size_t)sj * 128))[lane];
      acc.x = fmaf(wj, hv.x, acc.x);
      acc.y = fmaf(wj, hv.y, acc.y);
    }
  }
  float inv = isMu ? (1.0f / den_mu) : (1.0f / den_ls);
  float2 bv = isMu ? ((const float2*)b_mu)[lane] : ((const float2*)b_ls)[lane - 32];
  float2 o;
  o.x = fmaf(acc.x, inv, bv.x);
  o.y = fmaf(acc.y, inv, bv.y);
  if (isMu) ((float2*)(out_mu + (size_t)d * 64))[lane] = o;
  else      ((float2*)(out_ls + (size_t)d * 64))[lane - 32] = o;
}

// ---------------- launch ----------------

extern "C" void kernel_launch(void* const* d_in, const int* in_sizes, int n_in,
                              void* d_out, int out_size, void* d_ws, size_t ws_size,
                              hipStream_t stream) {
  const float* x = (const float*)d_in[0];
  const int* ei = (const int*)d_in[1];
  const float* W1 = (const float*)d_in[2];
  const float* a_src1 = (const float*)d_in[3];
  const float* a_dst1 = (const float*)d_in[4];
  const float* b1 = (const float*)d_in[5];
  const float* W_mu = (const float*)d_in[6];
  const float* a_src_mu = (const float*)d_in[7];
  const float* a_dst_mu = (const float*)d_in[8];
  const float* b_mu = (const float*)d_in[9];
  const float* W_ls = (const float*)d_in[10];
  const float* a_src_ls = (const float*)d_in[11];
  const float* a_dst_ls = (const float*)d_in[12];
  const float* b_ls = (const float*)d_in[13];

  const int N = in_sizes[0] / 128;  // 50000
  const int E = in_sizes[1] / 2;    // 800000
  const int NB = (N + 255) / 256;   // scan blocks (196 <= 256)

  uint8_t* p = (uint8_t*)d_ws;
  auto carve = [&](size_t bytes) -> void* {
    void* q = (void*)p;
    p += (bytes + 255) & ~(size_t)255;
    return q;
  };
  int* counts = (int*)carve((size_t)N * 4);
  int* excl = (int*)carve((size_t)N * 4);
  int* blockSums = (int*)carve((size_t)256 * 4);
  int* row_start = (int*)carve((size_t)(N + 1) * 4);
  int* cursor = (int*)carve((size_t)N * 4);
  int* esrc = (int*)carve((size_t)E * 4);
  float* H1 = (float*)carve((size_t)N * 128 * 4);  // reused as H2
  float* h1 = (float*)carve((size_t)N * 128 * 4);
  float* as1 = (float*)carve((size_t)N * 4);
  float* ad1 = (float*)carve((size_t)N * 4);
  float* asmu = (float*)carve((size_t)N * 4);
  float* admu = (float*)carve((size_t)N * 4);
  float* asls = (float*)carve((size_t)N * 4);
  float* adls = (float*)carve((size_t)N * 4);

  float* H2 = H1;

  hipMemsetAsync(counts, 0, (size_t)N * 4, stream);
  hist_kernel<<<(E + 255) / 256, 256, 0, stream>>>(ei, counts, E);
  scan_block_kernel<<<NB, 256, 0, stream>>>(counts, excl, blockSums, N);
  scan_sums_kernel<<<1, 256, 0, stream>>>(blockSums, row_start, NB, N);
  scan_final_kernel<<<NB, 256, 0, stream>>>(excl, blockSums, row_start, cursor, N);
  scatter_kernel<<<(E + 255) / 256, 256, 0, stream>>>(ei, cursor, esrc, E);

  gemm1_kernel<<<(N + 63) / 64, 256, 0, stream>>>(x, W1, a_src1, a_dst1, H1, as1, ad1, N);
  agg1_kernel<<<(N + 3) / 4, 256, 0, stream>>>(H1, as1, ad1, row_start, esrc, b1, h1, N);
  gemm2_kernel<<<(N + 63) / 64, 256, 0, stream>>>(h1, W_mu, W_ls, a_src_mu, a_dst_mu,
                                                  a_src_ls, a_dst_ls, H2, asmu, admu, asls, adls, N);
  float* out_mu = (float*)d_out;
  float* out_ls = out_mu + (size_t)N * 64;
  agg2_kernel<<<(N + 3) / 4, 256, 0, stream>>>(H2, asmu, admu, asls, adls, row_start, esrc,
                                               b_mu, b_ls, out_mu, out_ls, N);
}

// Round 3
// 267.944 us; speedup vs baseline: 1.9659x; 1.1724x over previous
//
#include <hip/hip_runtime.h>
#include <hip/hip_bf16.h>
#include <math.h>

// ---------------- helpers ----------------

__device__ __forceinline__ float wave_max64(float v) {
#pragma unroll
  for (int o = 32; o > 0; o >>= 1) v = fmaxf(v, __shfl_xor(v, o));
  return v;
}
__device__ __forceinline__ float wave_sum64(float v) {
#pragma unroll
  for (int o = 32; o > 0; o >>= 1) v += __shfl_xor(v, o);
  return v;
}
__device__ __forceinline__ float leaky02(float v) { return v > 0.0f ? v : 0.2f * v; }

// bf16 pack/unpack (RNE)
__device__ __forceinline__ unsigned short f2bf(float f) {
  unsigned u = __float_as_uint(f);
  u += 0x7FFF + ((u >> 16) & 1);
  return (unsigned short)(u >> 16);
}
// unpack 2 bf16 (packed lo|hi in a uint) to float2
__device__ __forceinline__ float2 bfp(unsigned v) {
  float2 r;
  r.x = __uint_as_float(v << 16);
  r.y = __uint_as_float(v & 0xFFFF0000u);
  return r;
}

// ---------------- CSR build ----------------

__global__ void hist_kernel(const int* __restrict__ ei, int* __restrict__ counts, int E) {
  int e = blockIdx.x * blockDim.x + threadIdx.x;
  if (e < E) atomicAdd(&counts[ei[E + e]], 1);
}

__global__ __launch_bounds__(256) void scan_block_kernel(
    const int* __restrict__ counts, int* __restrict__ excl, int* __restrict__ blockSums, int N) {
  __shared__ int lds[256];
  int i = blockIdx.x * 256 + threadIdx.x;
  int v = (i < N) ? counts[i] : 0;
  lds[threadIdx.x] = v;
  __syncthreads();
#pragma unroll
  for (int off = 1; off < 256; off <<= 1) {
    int t = ((int)threadIdx.x >= off) ? lds[threadIdx.x - off] : 0;
    __syncthreads();
    lds[threadIdx.x] += t;
    __syncthreads();
  }
  if (i < N) excl[i] = lds[threadIdx.x] - v;
  if (threadIdx.x == 255) blockSums[blockIdx.x] = lds[255];
}

__global__ __launch_bounds__(256) void scan_sums_kernel(
    int* __restrict__ blockSums, int* __restrict__ row_start, int NB, int N) {
  __shared__ int lds[256];
  int b = threadIdx.x;
  int v = (b < NB) ? blockSums[b] : 0;
  lds[b] = v;
  __syncthreads();
#pragma unroll
  for (int off = 1; off < 256; off <<= 1) {
    int t = ((int)threadIdx.x >= off) ? lds[threadIdx.x - off] : 0;
    __syncthreads();
    lds[threadIdx.x] += t;
    __syncthreads();
  }
  if (b < NB) blockSums[b] = lds[b] - v;
  if (b == NB - 1) row_start[N] = lds[b];
}

__global__ __launch_bounds__(256) void scan_final_kernel(
    const int* __restrict__ excl, const int* __restrict__ blockSums,
    int* __restrict__ row_start, int* __restrict__ cursor, int N) {
  int i = blockIdx.x * 256 + threadIdx.x;
  if (i < N) {
    int rs = excl[i] + blockSums[blockIdx.x];
    row_start[i] = rs;
    cursor[i] = rs;
  }
}

__global__ void scatter_kernel(const int* __restrict__ ei, int* __restrict__ cursor,
                               int* __restrict__ esrc, int E) {
  int e = blockIdx.x * blockDim.x + threadIdx.x;
  if (e < E) {
    int dst = ei[E + e];
    int pos = atomicAdd(&cursor[dst], 1);
    esrc[pos] = ei[e];
  }
}

// ---------------- GEMM: register-blocked, LDS tiled ----------------
// 256 threads; M_TILE=64, N=128, K chunks of 32. acc[4][8] per thread.
// Epilogues write bf16 feature tables for the gather kernels.

#define XIDX(k, m) ((k) * 64 + ((m) ^ ((((k) >> 2) & 7) << 3)))

__global__ __launch_bounds__(256) void gemm1_kernel(
    const float* __restrict__ X, const float* __restrict__ W,
    const float* __restrict__ a_src, const float* __restrict__ a_dst,
    unsigned short* __restrict__ Hb, float* __restrict__ asrc, float* __restrict__ adst, int N) {
  __shared__ float Xs[32 * 64];
  __shared__ float Ws[32 * 128];
  const int tid = threadIdx.x;
  const int tx = tid & 15, ty = tid >> 4;
  const int rowBase = blockIdx.x * 64;
  const int c0 = tx * 8;

  float acc[4][8];
#pragma unroll
  for (int r = 0; r < 4; ++r)
#pragma unroll
    for (int c = 0; c < 8; ++c) acc[r][c] = 0.f;

  for (int kc = 0; kc < 4; ++kc) {
    const int k0 = kc * 32;
#pragma unroll
    for (int j = 0; j < 2; ++j) {
      int i = tid + j * 256;
      int m = i >> 3, kq = i & 7;
      int row = rowBase + m;
      float4 v = make_float4(0.f, 0.f, 0.f, 0.f);
      if (row < N) v = *(const float4*)(X + (size_t)row * 128 + k0 + kq * 4);
      Xs[XIDX(kq * 4 + 0, m)] = v.x;
      Xs[XIDX(kq * 4 + 1, m)] = v.y;
      Xs[XIDX(kq * 4 + 2, m)] = v.z;
      Xs[XIDX(kq * 4 + 3, m)] = v.w;
    }
#pragma unroll
    for (int j = 0; j < 4; ++j) {
      int i = tid + j * 256;
      int k = i >> 5, c = (i & 31) * 4;
      *(float4*)&Ws[k * 128 + c] = *(const float4*)(W + (size_t)(k0 + k) * 128 + c);
    }
    __syncthreads();
#pragma unroll
    for (int k = 0; k < 32; ++k) {
      float4 a = *(const float4*)&Xs[k * 64 + ((ty * 4) ^ (((k >> 2) & 7) << 3))];
      float4 b0 = *(const float4*)&Ws[k * 128 + c0];
      float4 b1 = *(const float4*)&Ws[k * 128 + c0 + 4];
      float av[4] = {a.x, a.y, a.z, a.w};
      float bv[8] = {b0.x, b0.y, b0.z, b0.w, b1.x, b1.y, b1.z, b1.w};
#pragma unroll
      for (int r = 0; r < 4; ++r)
#pragma unroll
        for (int c = 0; c < 8; ++c) acc[r][c] = fmaf(av[r], bv[c], acc[r][c]);
    }
    __syncthreads();
  }

  float as[8], ds[8];
#pragma unroll
  for (int c = 0; c < 8; ++c) { as[c] = a_src[c0 + c]; ds[c] = a_dst[c0 + c]; }
#pragma unroll
  for (int r = 0; r < 4; ++r) {
    int row = rowBase + ty * 4 + r;
    if (row >= N) break;
    uint4 pk;
    pk.x = (unsigned)f2bf(acc[r][0]) | ((unsigned)f2bf(acc[r][1]) << 16);
    pk.y = (unsigned)f2bf(acc[r][2]) | ((unsigned)f2bf(acc[r][3]) << 16);
    pk.z = (unsigned)f2bf(acc[r][4]) | ((unsigned)f2bf(acc[r][5]) << 16);
    pk.w = (unsigned)f2bf(acc[r][6]) | ((unsigned)f2bf(acc[r][7]) << 16);
    *(uint4*)(Hb + (size_t)row * 128 + c0) = pk;
    float ps = 0.f, pd = 0.f;
#pragma unroll
    for (int c = 0; c < 8; ++c) { ps = fmaf(acc[r][c], as[c], ps); pd = fmaf(acc[r][c], ds[c], pd); }
#pragma unroll
    for (int o = 8; o > 0; o >>= 1) { ps += __shfl_xor(ps, o); pd += __shfl_xor(pd, o); }
    if (tx == 0) { asrc[row] = ps; adst[row] = pd; }
  }
}

__global__ __launch_bounds__(256) void gemm2_kernel(
    const float* __restrict__ X,
    const float* __restrict__ W_mu, const float* __restrict__ W_ls,
    const float* __restrict__ a_src_mu, const float* __restrict__ a_dst_mu,
    const float* __restrict__ a_src_ls, const float* __restrict__ a_dst_ls,
    unsigned short* __restrict__ Hb,
    float* __restrict__ as2, float* __restrict__ ad2, int N) {
  __shared__ float Xs[32 * 64];
  __shared__ float Ws[32 * 128];
  const int tid = threadIdx.x;
  const int tx = tid & 15, ty = tid >> 4;
  const int rowBase = blockIdx.x * 64;
  const int c0 = tx * 8;
  const bool isMu = tx < 8;

  float acc[4][8];
#pragma unroll
  for (int r = 0; r < 4; ++r)
#pragma unroll
    for (int c = 0; c < 8; ++c) acc[r][c] = 0.f;

  for (int kc = 0; kc < 4; ++kc) {
    const int k0 = kc * 32;
#pragma unroll
    for (int j = 0; j < 2; ++j) {
      int i = tid + j * 256;
      int m = i >> 3, kq = i & 7;
      int row = rowBase + m;
      float4 v = make_float4(0.f, 0.f, 0.f, 0.f);
      if (row < N) v = *(const float4*)(X + (size_t)row * 128 + k0 + kq * 4);
      Xs[XIDX(kq * 4 + 0, m)] = v.x;
      Xs[XIDX(kq * 4 + 1, m)] = v.y;
      Xs[XIDX(kq * 4 + 2, m)] = v.z;
      Xs[XIDX(kq * 4 + 3, m)] = v.w;
    }
#pragma unroll
    for (int j = 0; j < 2; ++j) {
      int i = tid + j * 256;
      int k = i >> 4, c = (i & 15) * 4;
      *(float4*)&Ws[k * 128 + c] = *(const float4*)(W_mu + (size_t)(k0 + k) * 64 + c);
      *(float4*)&Ws[k * 128 + 64 + c] = *(const float4*)(W_ls + (size_t)(k0 + k) * 64 + c);
    }
    __syncthreads();
#pragma unroll
    for (int k = 0; k < 32; ++k) {
      float4 a = *(const float4*)&Xs[k * 64 + ((ty * 4) ^ (((k >> 2) & 7) << 3))];
      float4 b0 = *(const float4*)&Ws[k * 128 + c0];
      float4 b1 = *(const float4*)&Ws[k * 128 + c0 + 4];
      float av[4] = {a.x, a.y, a.z, a.w};
      float bv[8] = {b0.x, b0.y, b0.z, b0.w, b1.x, b1.y, b1.z, b1.w};
#pragma unroll
      for (int r = 0; r < 4; ++r)
#pragma unroll
        for (int c = 0; c < 8; ++c) acc[r][c] = fmaf(av[r], bv[c], acc[r][c]);
    }
    __syncthreads();
  }

  float as[8], ds[8];
#pragma unroll
  for (int c = 0; c < 8; ++c) {
    int cc = isMu ? (c0 + c) : (c0 - 64 + c);
    as[c] = isMu ? a_src_mu[cc] : a_src_ls[cc];
    ds[c] = isMu ? a_dst_mu[cc] : a_dst_ls[cc];
  }
#pragma unroll
  for (int r = 0; r < 4; ++r) {
    int row = rowBase + ty * 4 + r;
    if (row >= N) break;
    uint4 pk;
    pk.x = (unsigned)f2bf(acc[r][0]) | ((unsigned)f2bf(acc[r][1]) << 16);
    pk.y = (unsigned)f2bf(acc[r][2]) | ((unsigned)f2bf(acc[r][3]) << 16);
    pk.z = (unsigned)f2bf(acc[r][4]) | ((unsigned)f2bf(acc[r][5]) << 16);
    pk.w = (unsigned)f2bf(acc[r][6]) | ((unsigned)f2bf(acc[r][7]) << 16);
    *(uint4*)(Hb + (size_t)row * 128 + c0) = pk;
    float ps = 0.f, pd = 0.f;
#pragma unroll
    for (int c = 0; c < 8; ++c) { ps = fmaf(acc[r][c], as[c], ps); pd = fmaf(acc[r][c], ds[c], pd); }
#pragma unroll
    for (int o = 4; o > 0; o >>= 1) { ps += __shfl_xor(ps, o); pd += __shfl_xor(pd, o); }
    if (tx == 0) { as2[2 * row] = ps; ad2[2 * row] = pd; }       // mu slot
    if (tx == 8) { as2[2 * row + 1] = ps; ad2[2 * row + 1] = pd; }  // ls slot
  }
}

// ---------------- Aggregation layer 1 (bf16 gather, fp32 math, + bias + ReLU) ----------------

__global__ __launch_bounds__(256) void agg1_kernel(
    const unsigned short* __restrict__ Hb, const float* __restrict__ asrc,
    const float* __restrict__ adst,
    const int* __restrict__ row_start, const int* __restrict__ esrc,
    const float* __restrict__ b, float* __restrict__ hout, int N) {
  int lane = threadIdx.x & 63;
  int d = (int)((blockIdx.x * blockDim.x + threadIdx.x) >> 6);
  if (d >= N) return;
  float ad = adst[d];
  float m = leaky02(asrc[d] + ad);  // self-loop logit
  float denom = 1.0f;
  float2 acc = bfp(((const unsigned*)(Hb + (size_t)d * 128))[lane]);
  int beg = row_start[d], end = row_start[d + 1];
  for (int base = beg; base < end; base += 64) {
    int nv = end - base;
    if (nv > 64) nv = 64;
    float e = -INFINITY;
    int s = 0;
    if (lane < nv) {
      s = esrc[base + lane];
      e = leaky02(asrc[s] + ad);
    }
    float cm = wave_max64(e);
    if (cm > m) {
      float sc = __expf(m - cm);
      denom *= sc; acc.x *= sc; acc.y *= sc;
      m = cm;
    }
    float w = __expf(e - m);
    denom += wave_sum64(w);
    int j = 0;
    for (; j + 4 <= nv; j += 4) {
      int s0 = __shfl(s, j), s1 = __shfl(s, j + 1), s2 = __shfl(s, j + 2), s3 = __shfl(s, j + 3);
      float w0 = __shfl(w, j), w1 = __shfl(w, j + 1), w2 = __shfl(w, j + 2), w3 = __shfl(w, j + 3);
      unsigned v0 = ((const unsigned*)(Hb + (size_t)s0 * 128))[lane];
      unsigned v1 = ((const unsigned*)(Hb + (size_t)s1 * 128))[lane];
      unsigned v2 = ((const unsigned*)(Hb + (size_t)s2 * 128))[lane];
      unsigned v3 = ((const unsigned*)(Hb + (size_t)s3 * 128))[lane];
      float2 f0 = bfp(v0), f1 = bfp(v1), f2 = bfp(v2), f3 = bfp(v3);
      acc.x = fmaf(w0, f0.x, acc.x); acc.y = fmaf(w0, f0.y, acc.y);
      acc.x = fmaf(w1, f1.x, acc.x); acc.y = fmaf(w1, f1.y, acc.y);
      acc.x = fmaf(w2, f2.x, acc.x); acc.y = fmaf(w2, f2.y, acc.y);
      acc.x = fmaf(w3, f3.x, acc.x); acc.y = fmaf(w3, f3.y, acc.y);
    }
    for (; j < nv; ++j) {
      int sj = __shfl(s, j);
      float wj = __shfl(w, j);
      float2 f = bfp(((const unsigned*)(Hb + (size_t)sj * 128))[lane]);
      acc.x = fmaf(wj, f.x, acc.x);
      acc.y = fmaf(wj, f.y, acc.y);
    }
  }
  float inv = 1.0f / denom;
  float2 bv = ((const float2*)b)[lane];
  float2 o;
  o.x = fmaxf(fmaf(acc.x, inv, bv.x), 0.0f);
  o.y = fmaxf(fmaf(acc.y, inv, bv.y), 0.0f);
  ((float2*)(hout + (size_t)d * 128))[lane] = o;
}

// ---------------- Aggregation layers 2+3 fused (mu lanes 0-31, ls lanes 32-63) ----------------

__global__ __launch_bounds__(256) void agg2_kernel(
    const unsigned short* __restrict__ Hb,
    const float2* __restrict__ as2, const float2* __restrict__ ad2,
    const int* __restrict__ row_start, const int* __restrict__ esrc,
    const float* __restrict__ b_mu, const float* __restrict__ b_ls,
    float* __restrict__ out_mu, float* __restrict__ out_ls, int N) {
  int lane = threadIdx.x & 63;
  int d = (int)((blockIdx.x * blockDim.x + threadIdx.x) >> 6);
  if (d >= N) return;
  bool isMu = lane < 32;
  float2 a2d = ad2[d];                 // {admu, adls}
  float2 a2s_self = as2[d];
  float m_mu = leaky02(a2s_self.x + a2d.x);
  float m_ls = leaky02(a2s_self.y + a2d.y);
  float den_mu = 1.0f, den_ls = 1.0f;
  float2 acc = bfp(((const unsigned*)(Hb + (size_t)d * 128))[lane]);
  int beg = row_start[d], end = row_start[d + 1];
  for (int base = beg; base < end; base += 64) {
    int nv = end - base;
    if (nv > 64) nv = 64;
    float e_mu = -INFINITY, e_ls = -INFINITY;
    int s = 0;
    if (lane < nv) {
      s = esrc[base + lane];
      float2 av = as2[s];
      e_mu = leaky02(av.x + a2d.x);
      e_ls = leaky02(av.y + a2d.y);
    }
    float cm_mu = wave_max64(e_mu);
    float cm_ls = wave_max64(e_ls);
    float sc_mu = 1.0f, sc_ls = 1.0f;
    if (cm_mu > m_mu) { sc_mu = __expf(m_mu - cm_mu); den_mu *= sc_mu; m_mu = cm_mu; }
    if (cm_ls > m_ls) { sc_ls = __expf(m_ls - cm_ls); den_ls *= sc_ls; m_ls = cm_ls; }
    float sc = isMu ? sc_mu : sc_ls;
    acc.x *= sc; acc.y *= sc;
    float w_mu = __expf(e_mu - m_mu);
    float w_ls = __expf(e_ls - m_ls);
    den_mu += wave_sum64(w_mu);
    den_ls += wave_sum64(w_ls);
    int j = 0;
    for (; j + 4 <= nv; j += 4) {
      int s0 = __shfl(s, j), s1 = __shfl(s, j + 1), s2 = __shfl(s, j + 2), s3 = __shfl(s, j + 3);
      float wm0 = __shfl(w_mu, j), wm1 = __shfl(w_mu, j + 1), wm2 = __shfl(w_mu, j + 2), wm3 = __shfl(w_mu, j + 3);
      float wl0 = __shfl(w_ls, j), wl1 = __shfl(w_ls, j + 1), wl2 = __shfl(w_ls, j + 2), wl3 = __shfl(w_ls, j + 3);
      float w0 = isMu ? wm0 : wl0, w1 = isMu ? wm1 : wl1, w2 = isMu ? wm2 : wl2, w3 = isMu ? wm3 : wl3;
      unsigned v0 = ((const unsigned*)(Hb + (size_t)s0 * 128))[lane];
      unsigned v1 = ((const unsigned*)(Hb + (size_t)s1 * 128))[lane];
      unsigned v2 = ((const unsigned*)(Hb + (size_t)s2 * 128))[lane];
      unsigned v3 = ((const unsigned*)(Hb + (size_t)s3 * 128))[lane];
      float2 f0 = bfp(v0), f1 = bfp(v1), f2 = bfp(v2), f3 = bfp(v3);
      acc.x = fmaf(w0, f0.x, acc.x); acc.y = fmaf(w0, f0.y, acc.y);
      acc.x = fmaf(w1, f1.x, acc.x); acc.y = fmaf(w1, f1.y, acc.y);
      acc.x = fmaf(w2, f2.x, acc.x); acc.y = fmaf(w2, f2.y, acc.y);
      acc.x = fmaf(w3, f3.x, acc.x); acc.y = fmaf(w3, f3.y, acc.y);
    }
    for (; j < nv; ++j) {
      float wj_mu = __shfl(w_mu, j);
      float wj_ls = __shfl(w_ls, j);
      float wj = isMu ? wj_mu : wj_ls;
      int sj = __shfl(s, j);
      float2 f = bfp(((const unsigned*)(Hb + (size_t)sj * 128))[lane]);
      acc.x = fmaf(wj, f.x, acc.x);
      acc.y = fmaf(wj, f.y, acc.y);
    }
  }
  float inv = isMu ? (1.0f / den_mu) : (1.0f / den_ls);
  float2 bv = isMu ? ((const float2*)b_mu)[lane] : ((const float2*)b_ls)[lane - 32];
  float2 o;
  o.x = fmaf(acc.x, inv, bv.x);
  o.y = fmaf(acc.y, inv, bv.y);
  if (isMu) ((float2*)(out_mu + (size_t)d * 64))[lane] = o;
  else      ((float2*)(out_ls + (size_t)d * 64))[lane - 32] = o;
}

// ---------------- launch ----------------

extern "C" void kernel_launch(void* const* d_in, const int* in_sizes, int n_in,
                              void* d_out, int out_size, void* d_ws, size_t ws_size,
                              hipStream_t stream) {
  const float* x = (const float*)d_in[0];
  const int* ei = (const int*)d_in[1];
  const float* W1 = (const float*)d_in[2];
  const float* a_src1 = (const float*)d_in[3];
  const float* a_dst1 = (const float*)d_in[4];
  const float* b1 = (const float*)d_in[5];
  const float* W_mu = (const float*)d_in[6];
  const float* a_src_mu = (const float*)d_in[7];
  const float* a_dst_mu = (const float*)d_in[8];
  const float* b_mu = (const float*)d_in[9];
  const float* W_ls = (const float*)d_in[10];
  const float* a_src_ls = (const float*)d_in[11];
  const float* a_dst_ls = (const float*)d_in[12];
  const float* b_ls = (const float*)d_in[13];

  const int N = in_sizes[0] / 128;  // 50000
  const int E = in_sizes[1] / 2;    // 800000
  const int NB = (N + 255) / 256;

  uint8_t* p = (uint8_t*)d_ws;
  auto carve = [&](size_t bytes) -> void* {
    void* q = (void*)p;
    p += (bytes + 255) & ~(size_t)255;
    return q;
  };
  int* counts = (int*)carve((size_t)N * 4);
  int* excl = (int*)carve((size_t)N * 4);
  int* blockSums = (int*)carve((size_t)256 * 4);
  int* row_start = (int*)carve((size_t)(N + 1) * 4);
  int* cursor = (int*)carve((size_t)N * 4);
  int* esrc = (int*)carve((size_t)E * 4);
  unsigned short* Hb1 = (unsigned short*)carve((size_t)N * 128 * 2);  // bf16; reused as Hb2
  float* h1 = (float*)carve((size_t)N * 128 * 4);
  float* as1 = (float*)carve((size_t)N * 4);
  float* ad1 = (float*)carve((size_t)N * 4);
  float* as2 = (float*)carve((size_t)N * 8);   // float2 {mu, ls}
  float* ad2 = (float*)carve((size_t)N * 8);

  unsigned short* Hb2 = Hb1;  // Hb1 dead after agg1

  hipMemsetAsync(counts, 0, (size_t)N * 4, stream);
  hist_kernel<<<(E + 255) / 256, 256, 0, stream>>>(ei, counts, E);
  scan_block_kernel<<<NB, 256, 0, stream>>>(counts, excl, blockSums, N);
  scan_sums_kernel<<<1, 256, 0, stream>>>(blockSums, row_start, NB, N);
  scan_final_kernel<<<NB, 256, 0, stream>>>(excl, blockSums, row_start, cursor, N);
  scatter_kernel<<<(E + 255) / 256, 256, 0, stream>>>(ei, cursor, esrc, E);

  gemm1_kernel<<<(N + 63) / 64, 256, 0, stream>>>(x, W1, a_src1, a_dst1, Hb1, as1, ad1, N);
  agg1_kernel<<<(N + 3) / 4, 256, 0, stream>>>(Hb1, as1, ad1, row_start, esrc, b1, h1, N);
  gemm2_kernel<<<(N + 63) / 64, 256, 0, stream>>>(h1, W_mu, W_ls, a_src_mu, a_dst_mu,
                                                  a_src_ls, a_dst_ls, Hb2, as2, ad2, N);
  float* out_mu = (float*)d_out;
  float* out_ls = out_mu + (size_t)N * 64;
  agg2_kernel<<<(N + 3) / 4, 256, 0, stream>>>(Hb2, (const float2*)as2, (const float2*)ad2,
                                               row_start, esrc, b_mu, b_ls, out_mu, out_ls, N);
}

// Round 4
// 208.410 us; speedup vs baseline: 2.5275x; 1.2857x over previous
//
#include <hip/hip_runtime.h>
#include <hip/hip_bf16.h>
#include <math.h>

// ---------------- helpers ----------------

__device__ __forceinline__ float wave_max64(float v) {
#pragma unroll
  for (int o = 32; o > 0; o >>= 1) v = fmaxf(v, __shfl_xor(v, o));
  return v;
}
__device__ __forceinline__ float wave_sum64(float v) {
#pragma unroll
  for (int o = 32; o > 0; o >>= 1) v += __shfl_xor(v, o);
  return v;
}
__device__ __forceinline__ float leaky02(float v) { return v > 0.0f ? v : 0.2f * v; }

// bf16 pack/unpack (RNE)
__device__ __forceinline__ unsigned short f2bf(float f) {
  unsigned u = __float_as_uint(f);
  u += 0x7FFF + ((u >> 16) & 1);
  return (unsigned short)(u >> 16);
}
__device__ __forceinline__ float2 bfp(unsigned v) {
  float2 r;
  r.x = __uint_as_float(v << 16);
  r.y = __uint_as_float(v & 0xFFFF0000u);
  return r;
}

// ---------------- CSR build: 2-level bucket sort ----------------
// bucket = dst >> 9 (512 dsts/bucket). NBUCK <= 128 (N <= 65536).

#define BSHIFT 9
#define BDSTS 512

__global__ __launch_bounds__(256) void bucket_hist_kernel(
    const int* __restrict__ ei, int* __restrict__ bcount, int E, int NBUCK) {
  __shared__ int h[128];
  if (threadIdx.x < 128) h[threadIdx.x] = 0;
  __syncthreads();
  for (int e = blockIdx.x * blockDim.x + threadIdx.x; e < E; e += gridDim.x * blockDim.x)
    atomicAdd(&h[ei[E + e] >> BSHIFT], 1);
  __syncthreads();
  if (threadIdx.x < NBUCK && h[threadIdx.x]) atomicAdd(&bcount[threadIdx.x], h[threadIdx.x]);
}

// single block of 128: exclusive scan of NBUCK (<=128) bucket counts
__global__ __launch_bounds__(128) void bucket_scan_kernel(
    const int* __restrict__ bcount, int* __restrict__ bstart, int* __restrict__ bcursor,
    int* __restrict__ row_start, int NBUCK, int E, int N) {
  __shared__ int lds[128];
  int t = threadIdx.x;
  int v = (t < NBUCK) ? bcount[t] : 0;
  lds[t] = v;
  __syncthreads();
#pragma unroll
  for (int off = 1; off < 128; off <<= 1) {
    int tmp = (t >= off) ? lds[t - off] : 0;
    __syncthreads();
    lds[t] += tmp;
    __syncthreads();
  }
  if (t < NBUCK) {
    int excl = lds[t] - v;
    bstart[t] = excl;
    bcursor[t] = excl;
  }
  if (t == 0) { bstart[NBUCK] = E; row_start[N] = E; }
}

// each block: 4096-edge chunk -> bucketed (src,dst) pair runs (block-exclusive regions)
#define CHUNK 4096
__global__ __launch_bounds__(256) void pair_scatter_kernel(
    const int* __restrict__ ei, int* __restrict__ bcursor, int2* __restrict__ pairs, int E) {
  __shared__ int h[128], base[128], cur[128];
  if (threadIdx.x < 128) { h[threadIdx.x] = 0; cur[threadIdx.x] = 0; }
  __syncthreads();
  int c0 = blockIdx.x * CHUNK;
  int c1 = min(c0 + CHUNK, E);
  for (int e = c0 + (int)threadIdx.x; e < c1; e += 256)
    atomicAdd(&h[ei[E + e] >> BSHIFT], 1);
  __syncthreads();
  if (threadIdx.x < 128 && h[threadIdx.x])
    base[threadIdx.x] = atomicAdd(&bcursor[threadIdx.x], h[threadIdx.x]);
  __syncthreads();
  for (int e = c0 + (int)threadIdx.x; e < c1; e += 256) {
    int dst = ei[E + e];
    int src = ei[e];
    int b = dst >> BSHIFT;
    int r = atomicAdd(&cur[b], 1);
    pairs[base[b] + r] = make_int2(src, dst);
  }
}

// one block per bucket: per-dst hist+scan -> row_start, then ranked scatter of esrc
__global__ __launch_bounds__(512) void fine_kernel(
    const int2* __restrict__ pairs, const int* __restrict__ bstart,
    int* __restrict__ row_start, int* __restrict__ esrc, int N) {
  __shared__ int h[BDSTS], sc[BDSTS], cur[BDSTS];
  int t = threadIdx.x;
  int b = blockIdx.x;
  int d0 = b << BSHIFT;
  int d1 = min(d0 + BDSTS, N);
  int beg = bstart[b], end = bstart[b + 1];
  h[t] = 0;
  __syncthreads();
  for (int i = beg + t; i < end; i += 512) atomicAdd(&h[pairs[i].y - d0], 1);
  __syncthreads();
  int v = h[t];
  sc[t] = v;
  __syncthreads();
#pragma unroll
  for (int off = 1; off < BDSTS; off <<= 1) {
    int tmp = (t >= off) ? sc[t - off] : 0;
    __syncthreads();
    sc[t] += tmp;
    __syncthreads();
  }
  int excl = sc[t] - v;
  if (d0 + t < d1) row_start[d0 + t] = beg + excl;
  cur[t] = excl;
  __syncthreads();
  for (int i = beg + t; i < end; i += 512) {
    int2 p = pairs[i];
    int r = atomicAdd(&cur[p.y - d0], 1);
    esrc[beg + r] = p.x;
  }
}

// ---------------- GEMM: register-blocked, LDS tiled ----------------

#define XIDX(k, m) ((k) * 64 + ((m) ^ ((((k) >> 2) & 7) << 3)))

__global__ __launch_bounds__(256) void gemm1_kernel(
    const float* __restrict__ X, const float* __restrict__ W,
    const float* __restrict__ a_src, const float* __restrict__ a_dst,
    unsigned short* __restrict__ Hb, float* __restrict__ asrc, float* __restrict__ adst, int N) {
  __shared__ float Xs[32 * 64];
  __shared__ float Ws[32 * 128];
  const int tid = threadIdx.x;
  const int tx = tid & 15, ty = tid >> 4;
  const int rowBase = blockIdx.x * 64;
  const int c0 = tx * 8;

  float acc[4][8];
#pragma unroll
  for (int r = 0; r < 4; ++r)
#pragma unroll
    for (int c = 0; c < 8; ++c) acc[r][c] = 0.f;

  for (int kc = 0; kc < 4; ++kc) {
    const int k0 = kc * 32;
#pragma unroll
    for (int j = 0; j < 2; ++j) {
      int i = tid + j * 256;
      int m = i >> 3, kq = i & 7;
      int row = rowBase + m;
      float4 v = make_float4(0.f, 0.f, 0.f, 0.f);
      if (row < N) v = *(const float4*)(X + (size_t)row * 128 + k0 + kq * 4);
      Xs[XIDX(kq * 4 + 0, m)] = v.x;
      Xs[XIDX(kq * 4 + 1, m)] = v.y;
      Xs[XIDX(kq * 4 + 2, m)] = v.z;
      Xs[XIDX(kq * 4 + 3, m)] = v.w;
    }
#pragma unroll
    for (int j = 0; j < 4; ++j) {
      int i = tid + j * 256;
      int k = i >> 5, c = (i & 31) * 4;
      *(float4*)&Ws[k * 128 + c] = *(const float4*)(W + (size_t)(k0 + k) * 128 + c);
    }
    __syncthreads();
#pragma unroll
    for (int k = 0; k < 32; ++k) {
      float4 a = *(const float4*)&Xs[k * 64 + ((ty * 4) ^ (((k >> 2) & 7) << 3))];
      float4 b0 = *(const float4*)&Ws[k * 128 + c0];
      float4 b1 = *(const float4*)&Ws[k * 128 + c0 + 4];
      float av[4] = {a.x, a.y, a.z, a.w};
      float bv[8] = {b0.x, b0.y, b0.z, b0.w, b1.x, b1.y, b1.z, b1.w};
#pragma unroll
      for (int r = 0; r < 4; ++r)
#pragma unroll
        for (int c = 0; c < 8; ++c) acc[r][c] = fmaf(av[r], bv[c], acc[r][c]);
    }
    __syncthreads();
  }

  float as[8], ds[8];
#pragma unroll
  for (int c = 0; c < 8; ++c) { as[c] = a_src[c0 + c]; ds[c] = a_dst[c0 + c]; }
#pragma unroll
  for (int r = 0; r < 4; ++r) {
    int row = rowBase + ty * 4 + r;
    if (row >= N) break;
    uint4 pk;
    pk.x = (unsigned)f2bf(acc[r][0]) | ((unsigned)f2bf(acc[r][1]) << 16);
    pk.y = (unsigned)f2bf(acc[r][2]) | ((unsigned)f2bf(acc[r][3]) << 16);
    pk.z = (unsigned)f2bf(acc[r][4]) | ((unsigned)f2bf(acc[r][5]) << 16);
    pk.w = (unsigned)f2bf(acc[r][6]) | ((unsigned)f2bf(acc[r][7]) << 16);
    *(uint4*)(Hb + (size_t)row * 128 + c0) = pk;
    float ps = 0.f, pd = 0.f;
#pragma unroll
    for (int c = 0; c < 8; ++c) { ps = fmaf(acc[r][c], as[c], ps); pd = fmaf(acc[r][c], ds[c], pd); }
#pragma unroll
    for (int o = 8; o > 0; o >>= 1) { ps += __shfl_xor(ps, o); pd += __shfl_xor(pd, o); }
    if (tx == 0) { asrc[row] = ps; adst[row] = pd; }
  }
}

__global__ __launch_bounds__(256) void gemm2_kernel(
    const float* __restrict__ X,
    const float* __restrict__ W_mu, const float* __restrict__ W_ls,
    const float* __restrict__ a_src_mu, const float* __restrict__ a_dst_mu,
    const float* __restrict__ a_src_ls, const float* __restrict__ a_dst_ls,
    unsigned short* __restrict__ Hb,
    float* __restrict__ as2, float* __restrict__ ad2, int N) {
  __shared__ float Xs[32 * 64];
  __shared__ float Ws[32 * 128];
  const int tid = threadIdx.x;
  const int tx = tid & 15, ty = tid >> 4;
  const int rowBase = blockIdx.x * 64;
  const int c0 = tx * 8;
  const bool isMu = tx < 8;

  float acc[4][8];
#pragma unroll
  for (int r = 0; r < 4; ++r)
#pragma unroll
    for (int c = 0; c < 8; ++c) acc[r][c] = 0.f;

  for (int kc = 0; kc < 4; ++kc) {
    const int k0 = kc * 32;
#pragma unroll
    for (int j = 0; j < 2; ++j) {
      int i = tid + j * 256;
      int m = i >> 3, kq = i & 7;
      int row = rowBase + m;
      float4 v = make_float4(0.f, 0.f, 0.f, 0.f);
      if (row < N) v = *(const float4*)(X + (size_t)row * 128 + k0 + kq * 4);
      Xs[XIDX(kq * 4 + 0, m)] = v.x;
      Xs[XIDX(kq * 4 + 1, m)] = v.y;
      Xs[XIDX(kq * 4 + 2, m)] = v.z;
      Xs[XIDX(kq * 4 + 3, m)] = v.w;
    }
#pragma unroll
    for (int j = 0; j < 2; ++j) {
      int i = tid + j * 256;
      int k = i >> 4, c = (i & 15) * 4;
      *(float4*)&Ws[k * 128 + c] = *(const float4*)(W_mu + (size_t)(k0 + k) * 64 + c);
      *(float4*)&Ws[k * 128 + 64 + c] = *(const float4*)(W_ls + (size_t)(k0 + k) * 64 + c);
    }
    __syncthreads();
#pragma unroll
    for (int k = 0; k < 32; ++k) {
      float4 a = *(const float4*)&Xs[k * 64 + ((ty * 4) ^ (((k >> 2) & 7) << 3))];
      float4 b0 = *(const float4*)&Ws[k * 128 + c0];
      float4 b1 = *(const float4*)&Ws[k * 128 + c0 + 4];
      float av[4] = {a.x, a.y, a.z, a.w};
      float bv[8] = {b0.x, b0.y, b0.z, b0.w, b1.x, b1.y, b1.z, b1.w};
#pragma unroll
      for (int r = 0; r < 4; ++r)
#pragma unroll
        for (int c = 0; c < 8; ++c) acc[r][c] = fmaf(av[r], bv[c], acc[r][c]);
    }
    __syncthreads();
  }

  float as[8], ds[8];
#pragma unroll
  for (int c = 0; c < 8; ++c) {
    int cc = isMu ? (c0 + c) : (c0 - 64 + c);
    as[c] = isMu ? a_src_mu[cc] : a_src_ls[cc];
    ds[c] = isMu ? a_dst_mu[cc] : a_dst_ls[cc];
  }
#pragma unroll
  for (int r = 0; r < 4; ++r) {
    int row = rowBase + ty * 4 + r;
    if (row >= N) break;
    uint4 pk;
    pk.x = (unsigned)f2bf(acc[r][0]) | ((unsigned)f2bf(acc[r][1]) << 16);
    pk.y = (unsigned)f2bf(acc[r][2]) | ((unsigned)f2bf(acc[r][3]) << 16);
    pk.z = (unsigned)f2bf(acc[r][4]) | ((unsigned)f2bf(acc[r][5]) << 16);
    pk.w = (unsigned)f2bf(acc[r][6]) | ((unsigned)f2bf(acc[r][7]) << 16);
    *(uint4*)(Hb + (size_t)row * 128 + c0) = pk;
    float ps = 0.f, pd = 0.f;
#pragma unroll
    for (int c = 0; c < 8; ++c) { ps = fmaf(acc[r][c], as[c], ps); pd = fmaf(acc[r][c], ds[c], pd); }
#pragma unroll
    for (int o = 4; o > 0; o >>= 1) { ps += __shfl_xor(ps, o); pd += __shfl_xor(pd, o); }
    if (tx == 0) { as2[2 * row] = ps; ad2[2 * row] = pd; }
    if (tx == 8) { as2[2 * row + 1] = ps; ad2[2 * row + 1] = pd; }
  }
}

// ---------------- Aggregation layer 1 (bf16 gather, fp32 math, + bias + ReLU) ----------------

__global__ __launch_bounds__(256) void agg1_kernel(
    const unsigned short* __restrict__ Hb, const float* __restrict__ asrc,
    const float* __restrict__ adst,
    const int* __restrict__ row_start, const int* __restrict__ esrc,
    const float* __restrict__ b, float* __restrict__ hout, int N) {
  int lane = threadIdx.x & 63;
  int d = (int)((blockIdx.x * blockDim.x + threadIdx.x) >> 6);
  if (d >= N) return;
  float ad = adst[d];
  float m = leaky02(asrc[d] + ad);
  float denom = 1.0f;
  float2 acc = bfp(((const unsigned*)(Hb + (size_t)d * 128))[lane]);
  int beg = row_start[d], end = row_start[d + 1];
  for (int base = beg; base < end; base += 64) {
    int nv = end - base;
    if (nv > 64) nv = 64;
    float e = -INFINITY;
    int s = 0;
    if (lane < nv) {
      s = esrc[base + lane];
      e = leaky02(asrc[s] + ad);
    }
    float cm = wave_max64(e);
    if (cm > m) {
      float sc = __expf(m - cm);
      denom *= sc; acc.x *= sc; acc.y *= sc;
      m = cm;
    }
    float w = __expf(e - m);
    denom += wave_sum64(w);
    int j = 0;
    for (; j + 4 <= nv; j += 4) {
      int s0 = __shfl(s, j), s1 = __shfl(s, j + 1), s2 = __shfl(s, j + 2), s3 = __shfl(s, j + 3);
      float w0 = __shfl(w, j), w1 = __shfl(w, j + 1), w2 = __shfl(w, j + 2), w3 = __shfl(w, j + 3);
      unsigned v0 = ((const unsigned*)(Hb + (size_t)s0 * 128))[lane];
      unsigned v1 = ((const unsigned*)(Hb + (size_t)s1 * 128))[lane];
      unsigned v2 = ((const unsigned*)(Hb + (size_t)s2 * 128))[lane];
      unsigned v3 = ((const unsigned*)(Hb + (size_t)s3 * 128))[lane];
      float2 f0 = bfp(v0), f1 = bfp(v1), f2 = bfp(v2), f3 = bfp(v3);
      acc.x = fmaf(w0, f0.x, acc.x); acc.y = fmaf(w0, f0.y, acc.y);
      acc.x = fmaf(w1, f1.x, acc.x); acc.y = fmaf(w1, f1.y, acc.y);
      acc.x = fmaf(w2, f2.x, acc.x); acc.y = fmaf(w2, f2.y, acc.y);
      acc.x = fmaf(w3, f3.x, acc.x); acc.y = fmaf(w3, f3.y, acc.y);
    }
    for (; j < nv; ++j) {
      int sj = __shfl(s, j);
      float wj = __shfl(w, j);
      float2 f = bfp(((const unsigned*)(Hb + (size_t)sj * 128))[lane]);
      acc.x = fmaf(wj, f.x, acc.x);
      acc.y = fmaf(wj, f.y, acc.y);
    }
  }
  float inv = 1.0f / denom;
  float2 bv = ((const float2*)b)[lane];
  float2 o;
  o.x = fmaxf(fmaf(acc.x, inv, bv.x), 0.0f);
  o.y = fmaxf(fmaf(acc.y, inv, bv.y), 0.0f);
  ((float2*)(hout + (size_t)d * 128))[lane] = o;
}

// ---------------- Aggregation layers 2+3 fused (mu lanes 0-31, ls lanes 32-63) ----------------

__global__ __launch_bounds__(256) void agg2_kernel(
    const unsigned short* __restrict__ Hb,
    const float2* __restrict__ as2, const float2* __restrict__ ad2,
    const int* __restrict__ row_start, const int* __restrict__ esrc,
    const float* __restrict__ b_mu, const float* __restrict__ b_ls,
    float* __restrict__ out_mu, float* __restrict__ out_ls, int N) {
  int lane = threadIdx.x & 63;
  int d = (int)((blockIdx.x * blockDim.x + threadIdx.x) >> 6);
  if (d >= N) return;
  bool isMu = lane < 32;
  float2 a2d = ad2[d];
  float2 a2s_self = as2[d];
  float m_mu = leaky02(a2s_self.x + a2d.x);
  float m_ls = leaky02(a2s_self.y + a2d.y);
  float den_mu = 1.0f, den_ls = 1.0f;
  float2 acc = bfp(((const unsigned*)(Hb + (size_t)d * 128))[lane]);
  int beg = row_start[d], end = row_start[d + 1];
  for (int base = beg; base < end; base += 64) {
    int nv = end - base;
    if (nv > 64) nv = 64;
    float e_mu = -INFINITY, e_ls = -INFINITY;
    int s = 0;
    if (lane < nv) {
      s = esrc[base + lane];
      float2 av = as2[s];
      e_mu = leaky02(av.x + a2d.x);
      e_ls = leaky02(av.y + a2d.y);
    }
    float cm_mu = wave_max64(e_mu);
    float cm_ls = wave_max64(e_ls);
    float sc_mu = 1.0f, sc_ls = 1.0f;
    if (cm_mu > m_mu) { sc_mu = __expf(m_mu - cm_mu); den_mu *= sc_mu; m_mu = cm_mu; }
    if (cm_ls > m_ls) { sc_ls = __expf(m_ls - cm_ls); den_ls *= sc_ls; m_ls = cm_ls; }
    float sc = isMu ? sc_mu : sc_ls;
    acc.x *= sc; acc.y *= sc;
    float w_mu = __expf(e_mu - m_mu);
    float w_ls = __expf(e_ls - m_ls);
    den_mu += wave_sum64(w_mu);
    den_ls += wave_sum64(w_ls);
    int j = 0;
    for (; j + 4 <= nv; j += 4) {
      int s0 = __shfl(s, j), s1 = __shfl(s, j + 1), s2 = __shfl(s, j + 2), s3 = __shfl(s, j + 3);
      float wm0 = __shfl(w_mu, j), wm1 = __shfl(w_mu, j + 1), wm2 = __shfl(w_mu, j + 2), wm3 = __shfl(w_mu, j + 3);
      float wl0 = __shfl(w_ls, j), wl1 = __shfl(w_ls, j + 1), wl2 = __shfl(w_ls, j + 2), wl3 = __shfl(w_ls, j + 3);
      float w0 = isMu ? wm0 : wl0, w1 = isMu ? wm1 : wl1, w2 = isMu ? wm2 : wl2, w3 = isMu ? wm3 : wl3;
      unsigned v0 = ((const unsigned*)(Hb + (size_t)s0 * 128))[lane];
      unsigned v1 = ((const unsigned*)(Hb + (size_t)s1 * 128))[lane];
      unsigned v2 = ((const unsigned*)(Hb + (size_t)s2 * 128))[lane];
      unsigned v3 = ((const unsigned*)(Hb + (size_t)s3 * 128))[lane];
      float2 f0 = bfp(v0), f1 = bfp(v1), f2 = bfp(v2), f3 = bfp(v3);
      acc.x = fmaf(w0, f0.x, acc.x); acc.y = fmaf(w0, f0.y, acc.y);
      acc.x = fmaf(w1, f1.x, acc.x); acc.y = fmaf(w1, f1.y, acc.y);
      acc.x = fmaf(w2, f2.x, acc.x); acc.y = fmaf(w2, f2.y, acc.y);
      acc.x = fmaf(w3, f3.x, acc.x); acc.y = fmaf(w3, f3.y, acc.y);
    }
    for (; j < nv; ++j) {
      float wj_mu = __shfl(w_mu, j);
      float wj_ls = __shfl(w_ls, j);
      float wj = isMu ? wj_mu : wj_ls;
      int sj = __shfl(s, j);
      float2 f = bfp(((const unsigned*)(Hb + (size_t)sj * 128))[lane]);
      acc.x = fmaf(wj, f.x, acc.x);
      acc.y = fmaf(wj, f.y, acc.y);
    }
  }
  float inv = isMu ? (1.0f / den_mu) : (1.0f / den_ls);
  float2 bv = isMu ? ((const float2*)b_mu)[lane] : ((const float2*)b_ls)[lane - 32];
  float2 o;
  o.x = fmaf(acc.x, inv, bv.x);
  o.y = fmaf(acc.y, inv, bv.y);
  if (isMu) ((float2*)(out_mu + (size_t)d * 64))[lane] = o;
  else      ((float2*)(out_ls + (size_t)d * 64))[lane - 32] = o;
}

// ---------------- launch ----------------

extern "C" void kernel_launch(void* const* d_in, const int* in_sizes, int n_in,
                              void* d_out, int out_size, void* d_ws, size_t ws_size,
                              hipStream_t stream) {
  const float* x = (const float*)d_in[0];
  const int* ei = (const int*)d_in[1];
  const float* W1 = (const float*)d_in[2];
  const float* a_src1 = (const float*)d_in[3];
  const float* a_dst1 = (const float*)d_in[4];
  const float* b1 = (const float*)d_in[5];
  const float* W_mu = (const float*)d_in[6];
  const float* a_src_mu = (const float*)d_in[7];
  const float* a_dst_mu = (const float*)d_in[8];
  const float* b_mu = (const float*)d_in[9];
  const float* W_ls = (const float*)d_in[10];
  const float* a_src_ls = (const float*)d_in[11];
  const float* a_dst_ls = (const float*)d_in[12];
  const float* b_ls = (const float*)d_in[13];

  const int N = in_sizes[0] / 128;  // 50000
  const int E = in_sizes[1] / 2;    // 800000
  const int NBUCK = (N + BDSTS - 1) >> BSHIFT;  // 98 (<=128)

  uint8_t* p = (uint8_t*)d_ws;
  auto carve = [&](size_t bytes) -> void* {
    void* q = (void*)p;
    p += (bytes + 255) & ~(size_t)255;
    return q;
  };
  int* bcount = (int*)carve((size_t)(NBUCK + 1) * 4);
  int* bstart = (int*)carve((size_t)(NBUCK + 1) * 4);
  int* bcursor = (int*)carve((size_t)NBUCK * 4);
  int* row_start = (int*)carve((size_t)(N + 1) * 4);
  int* esrc = (int*)carve((size_t)E * 4);
  int2* pairs = (int2*)carve((size_t)E * 8);
  unsigned short* Hb1 = (unsigned short*)carve((size_t)N * 128 * 2);  // bf16; reused as Hb2
  float* h1 = (float*)carve((size_t)N * 128 * 4);
  float* as1 = (float*)carve((size_t)N * 4);
  float* ad1 = (float*)carve((size_t)N * 4);
  float* as2 = (float*)carve((size_t)N * 8);
  float* ad2 = (float*)carve((size_t)N * 8);

  unsigned short* Hb2 = Hb1;

  hipMemsetAsync(bcount, 0, (size_t)(NBUCK + 1) * 4, stream);
  bucket_hist_kernel<<<(E + 2047) / 2048, 256, 0, stream>>>(ei, bcount, E, NBUCK);
  bucket_scan_kernel<<<1, 128, 0, stream>>>(bcount, bstart, bcursor, row_start, NBUCK, E, N);
  pair_scatter_kernel<<<(E + CHUNK - 1) / CHUNK, 256, 0, stream>>>(ei, bcursor, pairs, E);
  fine_kernel<<<NBUCK, 512, 0, stream>>>(pairs, bstart, row_start, esrc, N);

  gemm1_kernel<<<(N + 63) / 64, 256, 0, stream>>>(x, W1, a_src1, a_dst1, Hb1, as1, ad1, N);
  agg1_kernel<<<(N + 3) / 4, 256, 0, stream>>>(Hb1, as1, ad1, row_start, esrc, b1, h1, N);
  gemm2_kernel<<<(N + 63) / 64, 256, 0, stream>>>(h1, W_mu, W_ls, a_src_mu, a_dst_mu,
                                                  a_src_ls, a_dst_ls, Hb2, as2, ad2, N);
  float* out_mu = (float*)d_out;
  float* out_ls = out_mu + (size_t)N * 64;
  agg2_kernel<<<(N + 3) / 4, 256, 0, stream>>>(Hb2, (const float2*)as2, (const float2*)ad2,
                                               row_start, esrc, b_mu, b_ls, out_mu, out_ls, N);
}